// Round 1
// baseline (1318.719 us; speedup 1.0000x reference)
//
#include <hip/hip_runtime.h>
#include <cstdint>
#include <cstddef>

// Problem constants (fixed by the reference).
#define BN_ 32
#define DD_ 1024
#define TT_ 1000
#define LMAX_ 200
#define VC_ 80
#define BLANK_ 79
#define SS_ 401          // 2*LMAX+1
#define NEGV (-1e30f)

typedef _Float16 half8 __attribute__((ext_vector_type(8)));
typedef float f32x4 __attribute__((ext_vector_type(4)));

// Async global->LDS, 16B per lane. LDS dest is wave-uniform base + lane*16;
// our seg layout is arranged so seg*16 == waveuniform + lane*16 exactly.
__device__ __forceinline__ void async16(const void* g, void* l) {
  __builtin_amdgcn_global_load_lds(
      (const __attribute__((address_space(1))) unsigned int*)g,
      (__attribute__((address_space(3))) unsigned int*)l, 16, 0, 0);
}

// ---------------------------------------------------------------------------
// Batched transpose + cast f32 -> f16: out[z][c][r] = (f16) in[z][r][c]
// ---------------------------------------------------------------------------
__global__ void transpose_cast_kernel(const float* __restrict__ in,
                                      _Float16* __restrict__ out,
                                      int R, int C) {
  __shared__ float tile[32][33];
  size_t bo = (size_t)blockIdx.z * R * C;
  int c0 = blockIdx.x * 32, r0 = blockIdx.y * 32;
  int tx = threadIdx.x, ty = threadIdx.y;
#pragma unroll
  for (int k = 0; k < 32; k += 8) {
    int r = r0 + ty + k, c = c0 + tx;
    if (r < R && c < C) tile[ty + k][tx] = in[bo + (size_t)r * C + c];
  }
  __syncthreads();
#pragma unroll
  for (int k = 0; k < 32; k += 8) {
    int c = c0 + ty + k, r = r0 + tx;
    if (c < C && r < R) out[bo + (size_t)c * R + r] = (_Float16)tile[tx][ty + k];
  }
}

// ---------------------------------------------------------------------------
// GEMM1: H = relu(A[M,K] @ W1[K,N] + b1), A f16 row-major, Bt = W1^T [N,K] f16.
// 128x128 tile, BK=32, 256 threads (4 waves in 2x2), 16x16x32 f16 MFMA,
// global_load_lds width-16 staging (m97 structure).
// ---------------------------------------------------------------------------
__global__ __launch_bounds__(256) void gemm_relu_kernel(
    const _Float16* __restrict__ A, const _Float16* __restrict__ Bt,
    const float* __restrict__ bias, _Float16* __restrict__ H,
    int M, int N, int K) {
  constexpr int BK = 32;
  __shared__ __align__(16) _Float16 sA[128 * BK];
  __shared__ __align__(16) _Float16 sB[128 * BK];
  int tid = threadIdx.x;
  int wave = tid >> 6, lane = tid & 63;
  int quad = lane >> 4, r16 = lane & 15;
  int m0 = blockIdx.y * 128, n0 = blockIdx.x * 128;
  int moff = (wave >> 1) * 64, noff = (wave & 1) * 64;

  f32x4 acc[4][4];
#pragma unroll
  for (int i = 0; i < 4; ++i)
#pragma unroll
    for (int j = 0; j < 4; ++j) acc[i][j] = {0.f, 0.f, 0.f, 0.f};

  for (int kt = 0; kt < K; kt += BK) {
#pragma unroll
    for (int jj = 0; jj < 2; ++jj) {
      int seg = tid + 256 * jj;          // 512 16B segments per tile
      int row = seg >> 2, c8 = seg & 3;  // 4 segs per 32-elem row
      async16(A + (size_t)(m0 + row) * K + kt + c8 * 8, &sA[seg * 8]);
      async16(Bt + (size_t)(n0 + row) * K + kt + c8 * 8, &sB[seg * 8]);
    }
    __syncthreads();  // drains vmcnt -> LDS tiles visible
    half8 af[4], bfr[4];
#pragma unroll
    for (int i = 0; i < 4; ++i)
      af[i] = *(const half8*)&sA[(moff + i * 16 + r16) * BK + quad * 8];
#pragma unroll
    for (int j = 0; j < 4; ++j)
      bfr[j] = *(const half8*)&sB[(noff + j * 16 + r16) * BK + quad * 8];
#pragma unroll
    for (int i = 0; i < 4; ++i)
#pragma unroll
      for (int j = 0; j < 4; ++j)
        acc[i][j] = __builtin_amdgcn_mfma_f32_16x16x32_f16(af[i], bfr[j], acc[i][j], 0, 0, 0);
    __syncthreads();  // protect LDS before next staging
  }
  // Epilogue: bias + relu + cast f16. C/D layout: col=lane&15, row=quad*4+r.
#pragma unroll
  for (int j = 0; j < 4; ++j) {
    int n = n0 + noff + j * 16 + r16;
    float bv = bias[n];
#pragma unroll
    for (int i = 0; i < 4; ++i) {
#pragma unroll
      for (int r = 0; r < 4; ++r) {
        int m = m0 + moff + i * 16 + quad * 4 + r;
        float v = acc[i][j][r] + bv;
        v = fmaxf(v, 0.f);
        H[(size_t)m * N + n] = (_Float16)v;
      }
    }
  }
}

// ---------------------------------------------------------------------------
// GEMM2 + fused log_softmax: LP[m][v] = log_softmax(H[m,:] @ W2 + b2)
// N=80 = 5x16 frags; full row lives in one wave -> shfl_xor softmax.
// ---------------------------------------------------------------------------
__global__ __launch_bounds__(256) void gemm_lsm_kernel(
    const _Float16* __restrict__ A, const _Float16* __restrict__ Bt,
    const float* __restrict__ bias, float* __restrict__ LP, int M, int K) {
  constexpr int BK = 32;
  __shared__ __align__(16) _Float16 sA[128 * BK];
  __shared__ __align__(16) _Float16 sB[VC_ * BK];
  int tid = threadIdx.x;
  int wave = tid >> 6, lane = tid & 63;
  int quad = lane >> 4, r16 = lane & 15;
  int m0 = blockIdx.x * 128;

  f32x4 acc[2][5];
#pragma unroll
  for (int i = 0; i < 2; ++i)
#pragma unroll
    for (int j = 0; j < 5; ++j) acc[i][j] = {0.f, 0.f, 0.f, 0.f};

  for (int kt = 0; kt < K; kt += BK) {
#pragma unroll
    for (int jj = 0; jj < 2; ++jj) {
      int seg = tid + 256 * jj;
      int row = seg >> 2, c8 = seg & 3;
      async16(A + (size_t)(m0 + row) * K + kt + c8 * 8, &sA[seg * 8]);
    }
    {
      int seg = tid;  // segs 0..255 (rows 0..63)
      int row = seg >> 2, c8 = seg & 3;
      async16(Bt + (size_t)row * K + kt + c8 * 8, &sB[seg * 8]);
      if (wave == 0) {  // wave-uniform branch, all 64 lanes: segs 256..319
        int seg2 = 256 + lane;
        int row2 = seg2 >> 2, c82 = seg2 & 3;
        async16(Bt + (size_t)row2 * K + kt + c82 * 8, &sB[seg2 * 8]);
      }
    }
    __syncthreads();
    half8 af[2], bfr[5];
#pragma unroll
    for (int i = 0; i < 2; ++i)
      af[i] = *(const half8*)&sA[(wave * 32 + i * 16 + r16) * BK + quad * 8];
#pragma unroll
    for (int j = 0; j < 5; ++j)
      bfr[j] = *(const half8*)&sB[(j * 16 + r16) * BK + quad * 8];
#pragma unroll
    for (int i = 0; i < 2; ++i)
#pragma unroll
      for (int j = 0; j < 5; ++j)
        acc[i][j] = __builtin_amdgcn_mfma_f32_16x16x32_f16(af[i], bfr[j], acc[i][j], 0, 0, 0);
    __syncthreads();
  }
  float bv[5];
#pragma unroll
  for (int j = 0; j < 5; ++j) bv[j] = bias[j * 16 + r16];
#pragma unroll
  for (int i = 0; i < 2; ++i) {
#pragma unroll
    for (int rr = 0; rr < 4; ++rr) {
      float vals[5];
      float mx = -3.4e38f;
#pragma unroll
      for (int j = 0; j < 5; ++j) {
        vals[j] = acc[i][j][rr] + bv[j];
        mx = fmaxf(mx, vals[j]);
      }
#pragma unroll
      for (int d = 1; d < 16; d <<= 1) mx = fmaxf(mx, __shfl_xor(mx, d));
      float sm = 0.f;
#pragma unroll
      for (int j = 0; j < 5; ++j) sm += expf(vals[j] - mx);
#pragma unroll
      for (int d = 1; d < 16; d <<= 1) sm += __shfl_xor(sm, d);
      float lse = mx + logf(sm);
      int m = m0 + wave * 32 + i * 16 + quad * 4 + rr;  // m = b*T + t
      float* o = LP + (size_t)m * VC_;
#pragma unroll
      for (int j = 0; j < 5; ++j) o[j * 16 + r16] = vals[j] - lse;
    }
  }
}

// ---------------------------------------------------------------------------
// CTC forward DP. One block per batch element. alpha[401] in LDS, one thread
// per s; loader threads double-buffer the next lp row. 2 barriers per step.
// ---------------------------------------------------------------------------
__global__ __launch_bounds__(512) void ctc_dp_kernel(
    const float* __restrict__ LP, const int* __restrict__ targets,
    const int* __restrict__ dlen, const int* __restrict__ tlen,
    float* __restrict__ partial) {
  __shared__ float alpha[SS_];
  __shared__ float rowbuf[2][VC_];
  int b = blockIdx.x;
  int tid = threadIdx.x;
  const float* lpb = LP + (size_t)b * TT_ * VC_;
  int Tl = dlen[b];
  int Ll = tlen[b];
  int s = tid;
  bool isS = (s < SS_);
  int lab = BLANK_;
  bool allow = false;
  if (isS && (s & 1)) {
    lab = targets[b * LMAX_ + (s >> 1)];
    allow = (s >= 3) && (lab != BLANK_) &&
            (lab != targets[b * LMAX_ + (s >> 1) - 1]);
  }
  bool isLoader = (tid >= 416 && tid < 416 + VC_);
  int lv = tid - 416;
  if (tid < VC_) rowbuf[0][tid] = lpb[tid];
  if (isLoader) rowbuf[1][lv] = lpb[VC_ + lv];
  __syncthreads();
  float a = NEGV;
  if (isS) {
    if (s == 0) a = rowbuf[0][BLANK_];
    else if (s == 1) a = rowbuf[0][lab];
    alpha[s] = a;
  }
  __syncthreads();
  for (int t = 1; t < Tl; ++t) {
    int p = t & 1;
    float am1 = NEGV, am2 = NEGV, e = 0.f, ld = 0.f;
    if (isS) {
      if (s >= 1) am1 = alpha[s - 1];
      if (allow) am2 = alpha[s - 2];
      e = rowbuf[p][lab];
    }
    bool doload = isLoader && (t + 1 < Tl);
    if (doload) ld = lpb[(size_t)(t + 1) * VC_ + lv];
    __syncthreads();  // all alpha/row reads done
    if (isS) {
      float m1 = fmaxf(a, am1);
      float l12 = m1 + log1pf(expf(fminf(a, am1) - m1));
      float m2 = fmaxf(l12, am2);
      a = m2 + log1pf(expf(fminf(l12, am2) - m2)) + e;
      alpha[s] = a;
    }
    if (doload) rowbuf[1 - p][lv] = ld;
    __syncthreads();  // writes visible for next step
  }
  if (tid == 0) {
    float a1 = alpha[2 * Ll - 1];
    float a2 = alpha[2 * Ll];
    float m = fmaxf(a1, a2);
    float last = m + log1pf(expf(fminf(a1, a2) - m));
    float nll = (last > NEGV * 0.5f) ? -last : 0.f;
    partial[b] = nll / (float)Tl;
  }
}

__global__ void finalize_kernel(const float* __restrict__ partial,
                                float* __restrict__ out) {
  int l = threadIdx.x;
  float v = (l < BN_) ? partial[l] : 0.f;
#pragma unroll
  for (int d = 1; d < 64; d <<= 1) v += __shfl_xor(v, d);
  if (l == 0) out[0] = v * (1.f / BN_);
}

// ---------------------------------------------------------------------------
extern "C" void kernel_launch(void* const* d_in, const int* in_sizes, int n_in,
                              void* d_out, int out_size, void* d_ws, size_t ws_size,
                              hipStream_t stream) {
  const float* dec = (const float*)d_in[0];   // [B, D, T] f32
  const int* tgt   = (const int*)d_in[1];     // [B, LMAX]
  const int* dln   = (const int*)d_in[2];     // [B]
  const int* tln   = (const int*)d_in[3];     // [B]
  const float* W1  = (const float*)d_in[4];   // [D, D]
  const float* b1  = (const float*)d_in[5];   // [D]
  const float* W2  = (const float*)d_in[6];   // [D, V]
  const float* b2  = (const float*)d_in[7];   // [V]
  float* out = (float*)d_out;

  char* ws = (char*)d_ws;
  const size_t M = (size_t)BN_ * TT_;  // 32000
  // Workspace layout (all offsets 16B-aligned), total ~143.6 MB:
  _Float16* Af   = (_Float16*)(ws);                 // 65,536,000 B  [M, D] f16
  _Float16* Hf   = (_Float16*)(ws + 65536000);      // 65,536,000 B  [M, D] f16
  _Float16* W1T  = (_Float16*)(ws + 131072000);     //  2,097,152 B  [D, D] f16 (W1^T)
  _Float16* W2T  = (_Float16*)(ws + 133169152);     //    163,840 B  [V, D] f16 (W2^T)
  float* LPp     = (float*)(ws + 133332992);        // 10,240,000 B  [M, V] f32
  float* partial = (float*)(ws + 143572992);        //        128 B  [B] f32

  dim3 tb(32, 8, 1);
  // dec [b][d][t] -> Af [b*T + t][d]
  transpose_cast_kernel<<<dim3((TT_ + 31) / 32, DD_ / 32, BN_), tb, 0, stream>>>(dec, Af, DD_, TT_);
  // W1 [k][n] -> W1T [n][k]
  transpose_cast_kernel<<<dim3(DD_ / 32, DD_ / 32, 1), tb, 0, stream>>>(W1, W1T, DD_, DD_);
  // W2 [k][v] -> W2T [v][k]
  transpose_cast_kernel<<<dim3((VC_ + 31) / 32, DD_ / 32, 1), tb, 0, stream>>>(W2, W2T, DD_, VC_);

  gemm_relu_kernel<<<dim3(DD_ / 128, M / 128, 1), 256, 0, stream>>>(
      Af, W1T, b1, Hf, (int)M, DD_, DD_);
  gemm_lsm_kernel<<<dim3(M / 128, 1, 1), 256, 0, stream>>>(
      Hf, W2T, b2, LPp, (int)M, DD_);
  ctc_dp_kernel<<<dim3(BN_, 1, 1), 512, 0, stream>>>(LPp, tgt, dln, tln, partial);
  finalize_kernel<<<1, 64, 0, stream>>>(partial, out);
}

// Round 2
// 521.008 us; speedup vs baseline: 2.5311x; 2.5311x over previous
//
#include <hip/hip_runtime.h>
#include <cstdint>
#include <cstddef>

// Problem constants (fixed by the reference).
#define BN_ 32
#define DD_ 1024
#define TT_ 1000
#define LMAX_ 200
#define VC_ 80
#define BLANK_ 79
#define SS_ 401          // 2*LMAX+1
#define SPAD 512         // padded S: 64 lanes x 8 states
#define NEGV (-1e30f)

typedef _Float16 half8 __attribute__((ext_vector_type(8)));
typedef float f32x4 __attribute__((ext_vector_type(4)));

// Async global->LDS, 16B per lane. LDS dest is wave-uniform base + lane*16.
__device__ __forceinline__ void async16(const void* g, void* l) {
  __builtin_amdgcn_global_load_lds(
      (const __attribute__((address_space(1))) unsigned int*)g,
      (__attribute__((address_space(3))) unsigned int*)l, 16, 0, 0);
}

// ---------------------------------------------------------------------------
// Batched transpose + cast f32 -> f16: out[z][c][r] = (f16) in[z][r][c]
// ---------------------------------------------------------------------------
__global__ void transpose_cast_kernel(const float* __restrict__ in,
                                      _Float16* __restrict__ out,
                                      int R, int C) {
  __shared__ float tile[32][33];
  size_t bo = (size_t)blockIdx.z * R * C;
  int c0 = blockIdx.x * 32, r0 = blockIdx.y * 32;
  int tx = threadIdx.x, ty = threadIdx.y;
#pragma unroll
  for (int k = 0; k < 32; k += 8) {
    int r = r0 + ty + k, c = c0 + tx;
    if (r < R && c < C) tile[ty + k][tx] = in[bo + (size_t)r * C + c];
  }
  __syncthreads();
#pragma unroll
  for (int k = 0; k < 32; k += 8) {
    int c = c0 + ty + k, r = r0 + tx;
    if (c < C && r < R) out[bo + (size_t)c * R + r] = (_Float16)tile[tx][ty + k];
  }
}

// ---------------------------------------------------------------------------
// GEMM1: H = relu(A[M,K] @ W1[K,N] + b1)  (m97-style, unchanged from R1)
// ---------------------------------------------------------------------------
__global__ __launch_bounds__(256) void gemm_relu_kernel(
    const _Float16* __restrict__ A, const _Float16* __restrict__ Bt,
    const float* __restrict__ bias, _Float16* __restrict__ H,
    int M, int N, int K) {
  constexpr int BK = 32;
  __shared__ __align__(16) _Float16 sA[128 * BK];
  __shared__ __align__(16) _Float16 sB[128 * BK];
  int tid = threadIdx.x;
  int wave = tid >> 6, lane = tid & 63;
  int quad = lane >> 4, r16 = lane & 15;
  int m0 = blockIdx.y * 128, n0 = blockIdx.x * 128;
  int moff = (wave >> 1) * 64, noff = (wave & 1) * 64;

  f32x4 acc[4][4];
#pragma unroll
  for (int i = 0; i < 4; ++i)
#pragma unroll
    for (int j = 0; j < 4; ++j) acc[i][j] = {0.f, 0.f, 0.f, 0.f};

  for (int kt = 0; kt < K; kt += BK) {
#pragma unroll
    for (int jj = 0; jj < 2; ++jj) {
      int seg = tid + 256 * jj;
      int row = seg >> 2, c8 = seg & 3;
      async16(A + (size_t)(m0 + row) * K + kt + c8 * 8, &sA[seg * 8]);
      async16(Bt + (size_t)(n0 + row) * K + kt + c8 * 8, &sB[seg * 8]);
    }
    __syncthreads();
    half8 af[4], bfr[4];
#pragma unroll
    for (int i = 0; i < 4; ++i)
      af[i] = *(const half8*)&sA[(moff + i * 16 + r16) * BK + quad * 8];
#pragma unroll
    for (int j = 0; j < 4; ++j)
      bfr[j] = *(const half8*)&sB[(noff + j * 16 + r16) * BK + quad * 8];
#pragma unroll
    for (int i = 0; i < 4; ++i)
#pragma unroll
      for (int j = 0; j < 4; ++j)
        acc[i][j] = __builtin_amdgcn_mfma_f32_16x16x32_f16(af[i], bfr[j], acc[i][j], 0, 0, 0);
    __syncthreads();
  }
#pragma unroll
  for (int j = 0; j < 4; ++j) {
    int n = n0 + noff + j * 16 + r16;
    float bv = bias[n];
#pragma unroll
    for (int i = 0; i < 4; ++i) {
#pragma unroll
      for (int r = 0; r < 4; ++r) {
        int m = m0 + moff + i * 16 + quad * 4 + r;
        float v = acc[i][j][r] + bv;
        v = fmaxf(v, 0.f);
        H[(size_t)m * N + n] = (_Float16)v;
      }
    }
  }
}

// ---------------------------------------------------------------------------
// GEMM2 + fused log_softmax (unchanged from R1)
// ---------------------------------------------------------------------------
__global__ __launch_bounds__(256) void gemm_lsm_kernel(
    const _Float16* __restrict__ A, const _Float16* __restrict__ Bt,
    const float* __restrict__ bias, float* __restrict__ LP, int M, int K) {
  constexpr int BK = 32;
  __shared__ __align__(16) _Float16 sA[128 * BK];
  __shared__ __align__(16) _Float16 sB[VC_ * BK];
  int tid = threadIdx.x;
  int wave = tid >> 6, lane = tid & 63;
  int quad = lane >> 4, r16 = lane & 15;
  int m0 = blockIdx.x * 128;

  f32x4 acc[2][5];
#pragma unroll
  for (int i = 0; i < 2; ++i)
#pragma unroll
    for (int j = 0; j < 5; ++j) acc[i][j] = {0.f, 0.f, 0.f, 0.f};

  for (int kt = 0; kt < K; kt += BK) {
#pragma unroll
    for (int jj = 0; jj < 2; ++jj) {
      int seg = tid + 256 * jj;
      int row = seg >> 2, c8 = seg & 3;
      async16(A + (size_t)(m0 + row) * K + kt + c8 * 8, &sA[seg * 8]);
    }
    {
      int seg = tid;
      int row = seg >> 2, c8 = seg & 3;
      async16(Bt + (size_t)row * K + kt + c8 * 8, &sB[seg * 8]);
      if (wave == 0) {
        int seg2 = 256 + lane;
        int row2 = seg2 >> 2, c82 = seg2 & 3;
        async16(Bt + (size_t)row2 * K + kt + c82 * 8, &sB[seg2 * 8]);
      }
    }
    __syncthreads();
    half8 af[2], bfr[5];
#pragma unroll
    for (int i = 0; i < 2; ++i)
      af[i] = *(const half8*)&sA[(wave * 32 + i * 16 + r16) * BK + quad * 8];
#pragma unroll
    for (int j = 0; j < 5; ++j)
      bfr[j] = *(const half8*)&sB[(j * 16 + r16) * BK + quad * 8];
#pragma unroll
    for (int i = 0; i < 2; ++i)
#pragma unroll
      for (int j = 0; j < 5; ++j)
        acc[i][j] = __builtin_amdgcn_mfma_f32_16x16x32_f16(af[i], bfr[j], acc[i][j], 0, 0, 0);
    __syncthreads();
  }
  float bv[5];
#pragma unroll
  for (int j = 0; j < 5; ++j) bv[j] = bias[j * 16 + r16];
#pragma unroll
  for (int i = 0; i < 2; ++i) {
#pragma unroll
    for (int rr = 0; rr < 4; ++rr) {
      float vals[5];
      float mx = -3.4e38f;
#pragma unroll
      for (int j = 0; j < 5; ++j) {
        vals[j] = acc[i][j][rr] + bv[j];
        mx = fmaxf(mx, vals[j]);
      }
#pragma unroll
      for (int d = 1; d < 16; d <<= 1) mx = fmaxf(mx, __shfl_xor(mx, d));
      float sm = 0.f;
#pragma unroll
      for (int j = 0; j < 5; ++j) sm += expf(vals[j] - mx);
#pragma unroll
      for (int d = 1; d < 16; d <<= 1) sm += __shfl_xor(sm, d);
      float lse = mx + logf(sm);
      int m = m0 + wave * 32 + i * 16 + quad * 4 + rr;
      float* o = LP + (size_t)m * VC_;
#pragma unroll
      for (int j = 0; j < 5; ++j) o[j * 16 + r16] = vals[j] - lse;
    }
  }
}

// ---------------------------------------------------------------------------
// Emit precompute: EM[b][t][s] = exp(LP[b][t][label(s)]) for s<SS_, else 0.
// label(s) = targets[b][s>>1] if s odd, BLANK if s even.
// ---------------------------------------------------------------------------
__global__ __launch_bounds__(256) void emit_kernel(
    const float* __restrict__ LP, const int* __restrict__ targets,
    float* __restrict__ EM) {
  int idx = blockIdx.x * 256 + threadIdx.x;   // over B*T*SPAD (exact grid)
  int s = idx & (SPAD - 1);
  int bt = idx >> 9;
  float v = 0.f;
  if (s < SS_) {
    int lab = BLANK_;
    if (s & 1) {
      int b = bt / TT_;
      lab = targets[b * LMAX_ + (s >> 1)];
    }
    v = __expf(LP[(size_t)bt * VC_ + lab]);
  }
  EM[idx] = v;
}

// ---------------------------------------------------------------------------
// CTC forward DP, linear domain with per-lane block-floating-point scale.
// One wave (64 lanes) per batch element; lane l holds states s = l*8 .. l*8+7
// as beta[8] with true alpha = beta * 2^k (k per-lane int). No barriers, no
// transcendentals in the T-loop. Emit probs prefetched 8 steps deep.
// ---------------------------------------------------------------------------
__device__ __forceinline__ void dp_step(float (&bta)[8], int& k,
                                        const f32x4 e0, const f32x4 e1,
                                        const float (&am)[4], int lane) {
  float pm1 = __shfl_up(bta[7], 1);   // alpha[s0-1] (neighbor's r=7)
  float pm2 = __shfl_up(bta[6], 1);   // alpha[s0-2] (neighbor's r=6)
  int pk = __shfl_up(k, 1);
  if (lane == 0) { pm1 = 0.f; pm2 = 0.f; pk = k; }
  int knew = max(k, pk);              // adopt larger scale (frontier-safe)
  int dn = pk - knew;                 // <= 0
  pm1 = ldexpf(pm1, dn);
  pm2 = ldexpf(pm2, dn);
  int ds = k - knew;                  // <= 0
#pragma unroll
  for (int r = 0; r < 8; ++r) bta[r] = ldexpf(bta[r], ds);
  k = knew;
  float nb[8];
  // even s: alpha[s] + alpha[s-1]; odd s: + allow * alpha[s-2]
  nb[0] = (bta[0] + pm1) * e0.x;
  nb[1] = fmaf(am[0], pm1, bta[1] + bta[0]) * e0.y;
  nb[2] = (bta[2] + bta[1]) * e0.z;
  nb[3] = fmaf(am[1], bta[1], bta[3] + bta[2]) * e0.w;
  nb[4] = (bta[4] + bta[3]) * e1.x;
  nb[5] = fmaf(am[2], bta[3], bta[5] + bta[4]) * e1.y;
  nb[6] = (bta[6] + bta[5]) * e1.z;
  nb[7] = fmaf(am[3], bta[5], bta[7] + bta[6]) * e1.w;
#pragma unroll
  for (int r = 0; r < 8; ++r) bta[r] = nb[r];
}

__device__ __forceinline__ void dp_rescale(float (&bta)[8], int& k) {
  float m = fmaxf(fmaxf(fmaxf(bta[0], bta[1]), fmaxf(bta[2], bta[3])),
                  fmaxf(fmaxf(bta[4], bta[5]), fmaxf(bta[6], bta[7])));
  // all values >= 0; exponent via bit extraction (m==0 -> ex=-126, harmless:
  // dead lane's k drifts down, scale-adopt handles frontier arrival)
  int ex = (__float_as_int(m) >> 23) - 126;
  k += ex;
#pragma unroll
  for (int r = 0; r < 8; ++r) bta[r] = ldexpf(bta[r], -ex);
}

__global__ __launch_bounds__(64) void ctc_dp_kernel(
    const float* __restrict__ EM, const int* __restrict__ targets,
    const int* __restrict__ dlen, const int* __restrict__ tlen,
    float* __restrict__ partial) {
  __shared__ float sb[SPAD];
  __shared__ int sk[64];
  int b = blockIdx.x;
  int lane = threadIdx.x;  // 0..63
  const float* em = EM + (size_t)b * TT_ * SPAD + lane * 8;
  int Tl = dlen[b], Ll = tlen[b];

  // allow masks (as float 0/1) for odd r: s = lane*8 + 2j+1
  float am[4];
#pragma unroll
  for (int j = 0; j < 4; ++j) {
    int s = lane * 8 + 2 * j + 1;
    int li = s >> 1;
    bool a = false;
    if (s >= 3 && li < LMAX_) {
      int lab = targets[b * LMAX_ + li];
      a = (lab != BLANK_) && (lab != targets[b * LMAX_ + li - 1]);
    }
    am[j] = a ? 1.f : 0.f;
  }

  // init t=0: alpha0[0]=p0[blank]=EM[0][0], alpha0[1]=p0[tgt0]=EM[0][1]
  f32x4 r0a = *(const f32x4*)(em);
  float bta[8] = {0.f, 0.f, 0.f, 0.f, 0.f, 0.f, 0.f, 0.f};
  if (lane == 0) { bta[0] = r0a.x; bta[1] = r0a.y; }
  int k = 0;

  constexpr int PD = 8;  // prefetch depth (rows ahead)
  f32x4 pf[PD][2];
#pragma unroll
  for (int j = 0; j < PD; ++j) {
    int ri = min(1 + j, TT_ - 1);
    pf[j][0] = *(const f32x4*)(em + (size_t)ri * SPAD);
    pf[j][1] = *(const f32x4*)(em + (size_t)ri * SPAD + 4);
  }

  int t = 1;
  for (; t + (PD - 1) < Tl; t += PD) {
#pragma unroll
    for (int u = 0; u < PD; ++u) {
      dp_step(bta, k, pf[u][0], pf[u][1], am, lane);
      if (u & 1) dp_rescale(bta, k);
      int ri = min(t + u + PD, TT_ - 1);
      pf[u][0] = *(const f32x4*)(em + (size_t)ri * SPAD);
      pf[u][1] = *(const f32x4*)(em + (size_t)ri * SPAD + 4);
    }
  }
#pragma unroll
  for (int u = 0; u < PD; ++u) {
    if (t + u < Tl) {
      dp_step(bta, k, pf[u][0], pf[u][1], am, lane);
      if (u & 1) dp_rescale(bta, k);
    }
  }

  // final: last = log(alpha[2Ll-1] + alpha[2Ll]); nll = -last (0 if prob==0)
#pragma unroll
  for (int r = 0; r < 8; ++r) sb[lane * 8 + r] = bta[r];
  sk[lane] = k;
  __syncthreads();
  if (lane == 0) {
    int s1 = 2 * Ll - 1, s2 = 2 * Ll;
    float v1 = sb[s1], v2 = sb[s2];
    int k1 = sk[s1 >> 3], k2 = sk[s2 >> 3];
    int km = max(k1, k2);
    float v = ldexpf(v1, k1 - km) + ldexpf(v2, k2 - km);
    float nll = 0.f;
    if (v > 0.f) {
      float last = (log2f(v) + (float)km) * 0.69314718055994531f;
      nll = -last;
    }
    partial[b] = nll / (float)Tl;
  }
}

__global__ void finalize_kernel(const float* __restrict__ partial,
                                float* __restrict__ out) {
  int l = threadIdx.x;
  float v = (l < BN_) ? partial[l] : 0.f;
#pragma unroll
  for (int d = 1; d < 64; d <<= 1) v += __shfl_xor(v, d);
  if (l == 0) out[0] = v * (1.f / BN_);
}

// ---------------------------------------------------------------------------
extern "C" void kernel_launch(void* const* d_in, const int* in_sizes, int n_in,
                              void* d_out, int out_size, void* d_ws, size_t ws_size,
                              hipStream_t stream) {
  const float* dec = (const float*)d_in[0];   // [B, D, T] f32
  const int* tgt   = (const int*)d_in[1];     // [B, LMAX]
  const int* dln   = (const int*)d_in[2];     // [B]
  const int* tln   = (const int*)d_in[3];     // [B]
  const float* W1  = (const float*)d_in[4];   // [D, D]
  const float* b1  = (const float*)d_in[5];   // [D]
  const float* W2  = (const float*)d_in[6];   // [D, V]
  const float* b2  = (const float*)d_in[7];   // [V]
  float* out = (float*)d_out;

  char* ws = (char*)d_ws;
  const size_t M = (size_t)BN_ * TT_;  // 32000
  // Workspace layout (~143.6 MB). EM reuses Af's region (Af dead after GEMM1).
  _Float16* Af   = (_Float16*)(ws);                 // 65,536,000 B  [M, D] f16
  float* EM      = (float*)(ws);                    // 65,536,000 B  [B,T,SPAD] f32 (aliases Af)
  _Float16* Hf   = (_Float16*)(ws + 65536000);      // 65,536,000 B  [M, D] f16
  _Float16* W1T  = (_Float16*)(ws + 131072000);     //  2,097,152 B  [D, D] f16 (W1^T)
  _Float16* W2T  = (_Float16*)(ws + 133169152);     //    163,840 B  [V, D] f16 (W2^T)
  float* LPp     = (float*)(ws + 133332992);        // 10,240,000 B  [M, V] f32
  float* partial = (float*)(ws + 143572992);        //        128 B  [B] f32

  dim3 tb(32, 8, 1);
  transpose_cast_kernel<<<dim3((TT_ + 31) / 32, DD_ / 32, BN_), tb, 0, stream>>>(dec, Af, DD_, TT_);
  transpose_cast_kernel<<<dim3(DD_ / 32, DD_ / 32, 1), tb, 0, stream>>>(W1, W1T, DD_, DD_);
  transpose_cast_kernel<<<dim3((VC_ + 31) / 32, DD_ / 32, 1), tb, 0, stream>>>(W2, W2T, DD_, VC_);

  gemm_relu_kernel<<<dim3(DD_ / 128, M / 128, 1), 256, 0, stream>>>(
      Af, W1T, b1, Hf, (int)M, DD_, DD_);
  gemm_lsm_kernel<<<dim3(M / 128, 1, 1), 256, 0, stream>>>(
      Hf, W2T, b2, LPp, (int)M, DD_);
  emit_kernel<<<dim3((BN_ * TT_ * SPAD) / 256, 1, 1), 256, 0, stream>>>(LPp, tgt, EM);
  ctc_dp_kernel<<<dim3(BN_, 1, 1), 64, 0, stream>>>(EM, tgt, dln, tln, partial);
  finalize_kernel<<<1, 64, 0, stream>>>(partial, out);
}

// Round 3
// 455.716 us; speedup vs baseline: 2.8937x; 1.1433x over previous
//
#include <hip/hip_runtime.h>
#include <cstdint>
#include <cstddef>

// Problem constants (fixed by the reference).
#define BN_ 32
#define DD_ 1024
#define TT_ 1000
#define LMAX_ 200
#define VC_ 80
#define BLANK_ 79
#define SS_ 401          // 2*LMAX+1
#define SPAD 512         // padded S: 64 lanes x 8 states
#define NEGV (-1e30f)

typedef _Float16 half8 __attribute__((ext_vector_type(8)));
typedef float f32x4 __attribute__((ext_vector_type(4)));

// Async global->LDS, 16B per lane. LDS dest is wave-uniform base + lane*16.
__device__ __forceinline__ void async16(const void* g, void* l) {
  __builtin_amdgcn_global_load_lds(
      (const __attribute__((address_space(1))) unsigned int*)g,
      (__attribute__((address_space(3))) unsigned int*)l, 16, 0, 0);
}

// ---------------------------------------------------------------------------
// Batched transpose + cast f32 -> f16: out[z][c][r] = (f16) in[z][r][c]
// ---------------------------------------------------------------------------
__global__ void transpose_cast_kernel(const float* __restrict__ in,
                                      _Float16* __restrict__ out,
                                      int R, int C) {
  __shared__ float tile[32][33];
  size_t bo = (size_t)blockIdx.z * R * C;
  int c0 = blockIdx.x * 32, r0 = blockIdx.y * 32;
  int tx = threadIdx.x, ty = threadIdx.y;
#pragma unroll
  for (int k = 0; k < 32; k += 8) {
    int r = r0 + ty + k, c = c0 + tx;
    if (r < R && c < C) tile[ty + k][tx] = in[bo + (size_t)r * C + c];
  }
  __syncthreads();
#pragma unroll
  for (int k = 0; k < 32; k += 8) {
    int c = c0 + ty + k, r = r0 + tx;
    if (c < C && r < R) out[bo + (size_t)c * R + r] = (_Float16)tile[tx][ty + k];
  }
}

// ---------------------------------------------------------------------------
// GEMM1: H = relu(A[M,K] @ W1[K,N] + b1)  (m97-style)
// ---------------------------------------------------------------------------
__global__ __launch_bounds__(256) void gemm_relu_kernel(
    const _Float16* __restrict__ A, const _Float16* __restrict__ Bt,
    const float* __restrict__ bias, _Float16* __restrict__ H,
    int M, int N, int K) {
  constexpr int BK = 32;
  __shared__ __align__(16) _Float16 sA[128 * BK];
  __shared__ __align__(16) _Float16 sB[128 * BK];
  int tid = threadIdx.x;
  int wave = tid >> 6, lane = tid & 63;
  int quad = lane >> 4, r16 = lane & 15;
  int m0 = blockIdx.y * 128, n0 = blockIdx.x * 128;
  int moff = (wave >> 1) * 64, noff = (wave & 1) * 64;

  f32x4 acc[4][4];
#pragma unroll
  for (int i = 0; i < 4; ++i)
#pragma unroll
    for (int j = 0; j < 4; ++j) acc[i][j] = {0.f, 0.f, 0.f, 0.f};

  for (int kt = 0; kt < K; kt += BK) {
#pragma unroll
    for (int jj = 0; jj < 2; ++jj) {
      int seg = tid + 256 * jj;
      int row = seg >> 2, c8 = seg & 3;
      async16(A + (size_t)(m0 + row) * K + kt + c8 * 8, &sA[seg * 8]);
      async16(Bt + (size_t)(n0 + row) * K + kt + c8 * 8, &sB[seg * 8]);
    }
    __syncthreads();
    half8 af[4], bfr[4];
#pragma unroll
    for (int i = 0; i < 4; ++i)
      af[i] = *(const half8*)&sA[(moff + i * 16 + r16) * BK + quad * 8];
#pragma unroll
    for (int j = 0; j < 4; ++j)
      bfr[j] = *(const half8*)&sB[(noff + j * 16 + r16) * BK + quad * 8];
#pragma unroll
    for (int i = 0; i < 4; ++i)
#pragma unroll
      for (int j = 0; j < 4; ++j)
        acc[i][j] = __builtin_amdgcn_mfma_f32_16x16x32_f16(af[i], bfr[j], acc[i][j], 0, 0, 0);
    __syncthreads();
  }
#pragma unroll
  for (int j = 0; j < 4; ++j) {
    int n = n0 + noff + j * 16 + r16;
    float bv = bias[n];
#pragma unroll
    for (int i = 0; i < 4; ++i) {
#pragma unroll
      for (int r = 0; r < 4; ++r) {
        int m = m0 + moff + i * 16 + quad * 4 + r;
        float v = acc[i][j][r] + bv;
        v = fmaxf(v, 0.f);
        H[(size_t)m * N + n] = (_Float16)v;
      }
    }
  }
}

// ---------------------------------------------------------------------------
// GEMM2 + fused log_softmax
// ---------------------------------------------------------------------------
__global__ __launch_bounds__(256) void gemm_lsm_kernel(
    const _Float16* __restrict__ A, const _Float16* __restrict__ Bt,
    const float* __restrict__ bias, float* __restrict__ LP, int M, int K) {
  constexpr int BK = 32;
  __shared__ __align__(16) _Float16 sA[128 * BK];
  __shared__ __align__(16) _Float16 sB[VC_ * BK];
  int tid = threadIdx.x;
  int wave = tid >> 6, lane = tid & 63;
  int quad = lane >> 4, r16 = lane & 15;
  int m0 = blockIdx.x * 128;

  f32x4 acc[2][5];
#pragma unroll
  for (int i = 0; i < 2; ++i)
#pragma unroll
    for (int j = 0; j < 5; ++j) acc[i][j] = {0.f, 0.f, 0.f, 0.f};

  for (int kt = 0; kt < K; kt += BK) {
#pragma unroll
    for (int jj = 0; jj < 2; ++jj) {
      int seg = tid + 256 * jj;
      int row = seg >> 2, c8 = seg & 3;
      async16(A + (size_t)(m0 + row) * K + kt + c8 * 8, &sA[seg * 8]);
    }
    {
      int seg = tid;
      int row = seg >> 2, c8 = seg & 3;
      async16(Bt + (size_t)row * K + kt + c8 * 8, &sB[seg * 8]);
      if (wave == 0) {
        int seg2 = 256 + lane;
        int row2 = seg2 >> 2, c82 = seg2 & 3;
        async16(Bt + (size_t)row2 * K + kt + c82 * 8, &sB[seg2 * 8]);
      }
    }
    __syncthreads();
    half8 af[2], bfr[5];
#pragma unroll
    for (int i = 0; i < 2; ++i)
      af[i] = *(const half8*)&sA[(wave * 32 + i * 16 + r16) * BK + quad * 8];
#pragma unroll
    for (int j = 0; j < 5; ++j)
      bfr[j] = *(const half8*)&sB[(j * 16 + r16) * BK + quad * 8];
#pragma unroll
    for (int i = 0; i < 2; ++i)
#pragma unroll
      for (int j = 0; j < 5; ++j)
        acc[i][j] = __builtin_amdgcn_mfma_f32_16x16x32_f16(af[i], bfr[j], acc[i][j], 0, 0, 0);
    __syncthreads();
  }
  float bv[5];
#pragma unroll
  for (int j = 0; j < 5; ++j) bv[j] = bias[j * 16 + r16];
#pragma unroll
  for (int i = 0; i < 2; ++i) {
#pragma unroll
    for (int rr = 0; rr < 4; ++rr) {
      float vals[5];
      float mx = -3.4e38f;
#pragma unroll
      for (int j = 0; j < 5; ++j) {
        vals[j] = acc[i][j][rr] + bv[j];
        mx = fmaxf(mx, vals[j]);
      }
#pragma unroll
      for (int d = 1; d < 16; d <<= 1) mx = fmaxf(mx, __shfl_xor(mx, d));
      float sm = 0.f;
#pragma unroll
      for (int j = 0; j < 5; ++j) sm += expf(vals[j] - mx);
#pragma unroll
      for (int d = 1; d < 16; d <<= 1) sm += __shfl_xor(sm, d);
      float lse = mx + logf(sm);
      int m = m0 + wave * 32 + i * 16 + quad * 4 + rr;
      float* o = LP + (size_t)m * VC_;
#pragma unroll
      for (int j = 0; j < 5; ++j) o[j * 16 + r16] = vals[j] - lse;
    }
  }
}

// ---------------------------------------------------------------------------
// Emit precompute: EM[b][t][s] = exp(LP[b][t][label(s)]) for s<SS_, else 0.
// ---------------------------------------------------------------------------
__global__ __launch_bounds__(256) void emit_kernel(
    const float* __restrict__ LP, const int* __restrict__ targets,
    float* __restrict__ EM) {
  int idx = blockIdx.x * 256 + threadIdx.x;
  int s = idx & (SPAD - 1);
  int bt = idx >> 9;
  float v = 0.f;
  if (s < SS_) {
    int lab = BLANK_;
    if (s & 1) {
      int b = bt / TT_;
      lab = targets[b * LMAX_ + (s >> 1)];
    }
    v = __expf(LP[(size_t)bt * VC_ + lab]);
  }
  EM[idx] = v;
}

// ---------------------------------------------------------------------------
// CTC DP, forward/backward split. Linear domain, per-lane block-float scale.
// Block = 128 threads: wave 0 runs forward alpha t=1..tm; wave 1 runs the
// reverse DP g_{t-1} = A^T (e_t . g_t) for t=Tl-1..tm+1. Then
// P = sum_s alpha_tm[s] * g_tm[s], reduced with scale-aware butterfly.
// ---------------------------------------------------------------------------
__device__ __forceinline__ void dp_step_fwd(float (&bta)[8], int& k,
                                            const f32x4 e0, const f32x4 e1,
                                            const float (&am)[4], int lane) {
  float pm1 = __shfl_up(bta[7], 1);   // alpha[s0-1] (prev lane r=7)
  int pk = __shfl_up(k, 1);
  if (lane == 0) { pm1 = 0.f; pk = k; }
  int knew = max(k, pk);
  pm1 = ldexpf(pm1, pk - knew);
  int ds = k - knew;
#pragma unroll
  for (int r = 0; r < 8; ++r) bta[r] = ldexpf(bta[r], ds);
  k = knew;
  float nb[8];
  nb[0] = (bta[0] + pm1) * e0.x;
  nb[1] = fmaf(am[0], pm1, bta[1] + bta[0]) * e0.y;
  nb[2] = (bta[2] + bta[1]) * e0.z;
  nb[3] = fmaf(am[1], bta[1], bta[3] + bta[2]) * e0.w;
  nb[4] = (bta[4] + bta[3]) * e1.x;
  nb[5] = fmaf(am[2], bta[3], bta[5] + bta[4]) * e1.y;
  nb[6] = (bta[6] + bta[5]) * e1.z;
  nb[7] = fmaf(am[3], bta[5], bta[7] + bta[6]) * e1.w;
#pragma unroll
  for (int r = 0; r < 8; ++r) bta[r] = nb[r];
}

// reverse: g'[s] = gh[s] + gh[s+1] + allow(s+2)*gh[s+2],  gh = e . g
__device__ __forceinline__ void dp_step_bwd(float (&g)[8], int& k,
                                            const f32x4 e0, const f32x4 e1,
                                            const float (&amB)[4], int lane) {
  float gh[8];
  gh[0] = g[0] * e0.x; gh[1] = g[1] * e0.y;
  gh[2] = g[2] * e0.z; gh[3] = g[3] * e0.w;
  gh[4] = g[4] * e1.x; gh[5] = g[5] * e1.y;
  gh[6] = g[6] * e1.z; gh[7] = g[7] * e1.w;
  float qm1 = __shfl_down(gh[0], 1);  // next lane gh[0]
  float qm2 = __shfl_down(gh[1], 1);  // next lane gh[1]
  int nk = __shfl_down(k, 1);
  if (lane == 63) { qm1 = 0.f; qm2 = 0.f; nk = k; }
  int knew = max(k, nk);
  int dq = nk - knew;
  qm1 = ldexpf(qm1, dq);
  qm2 = ldexpf(qm2, dq);
  int ds = k - knew;
#pragma unroll
  for (int r = 0; r < 8; ++r) gh[r] = ldexpf(gh[r], ds);
  k = knew;
  g[0] = gh[0] + gh[1];
  g[1] = fmaf(amB[0], gh[3], gh[1] + gh[2]);
  g[2] = gh[2] + gh[3];
  g[3] = fmaf(amB[1], gh[5], gh[3] + gh[4]);
  g[4] = gh[4] + gh[5];
  g[5] = fmaf(amB[2], gh[7], gh[5] + gh[6]);
  g[6] = gh[6] + gh[7];
  g[7] = fmaf(amB[3], qm2, gh[7] + qm1);
}

__device__ __forceinline__ void dp_rescale(float (&v)[8], int& k) {
  float m = fmaxf(fmaxf(fmaxf(v[0], v[1]), fmaxf(v[2], v[3])),
                  fmaxf(fmaxf(v[4], v[5]), fmaxf(v[6], v[7])));
  int ex = (__float_as_int(m) >> 23) - 126;  // m>=0; m==0 -> harmless drift
  k += ex;
#pragma unroll
  for (int r = 0; r < 8; ++r) v[r] = ldexpf(v[r], -ex);
}

// allow(s) = s odd, s>=3, label(s)!=BLANK, label(s)!=label(s-2)
__device__ __forceinline__ float allow_f(const int* __restrict__ tg, int s) {
  if (!(s & 1) || s < 3) return 0.f;
  int li = s >> 1;
  if (li >= LMAX_) return 0.f;
  int lab = tg[li];
  return (lab != BLANK_ && lab != tg[li - 1]) ? 1.f : 0.f;
}

__global__ __launch_bounds__(128) void ctc_dp_kernel(
    const float* __restrict__ EM, const int* __restrict__ targets,
    const int* __restrict__ dlen, const int* __restrict__ tlen,
    float* __restrict__ partial) {
  __shared__ float sg[SPAD];
  __shared__ int skg[64];
  int b = blockIdx.x;
  int wave = threadIdx.x >> 6;
  int lane = threadIdx.x & 63;
  const float* em = EM + (size_t)b * TT_ * SPAD + lane * 8;
  const int* tg = targets + b * LMAX_;
  int Tl = dlen[b], Ll = tlen[b];
  int tm = Tl >> 1;  // cut point: forward owns e_0..e_tm, backward e_{tm+1}..e_{Tl-1}

  constexpr int PD = 8;
  f32x4 pf[PD][2];
  float v[8];
  int k = 0;

  if (wave == 0) {
    // ---- forward ----
    float am[4];
#pragma unroll
    for (int j = 0; j < 4; ++j) am[j] = allow_f(tg, lane * 8 + 2 * j + 1);
    f32x4 r0a = *(const f32x4*)(em);
#pragma unroll
    for (int r = 0; r < 8; ++r) v[r] = 0.f;
    if (lane == 0) { v[0] = r0a.x; v[1] = r0a.y; }
#pragma unroll
    for (int j = 0; j < PD; ++j) {
      int ri = min(1 + j, TT_ - 1);
      pf[j][0] = *(const f32x4*)(em + (size_t)ri * SPAD);
      pf[j][1] = *(const f32x4*)(em + (size_t)ri * SPAD + 4);
    }
    int t = 1;
    for (; t + (PD - 1) <= tm; t += PD) {
#pragma unroll
      for (int u = 0; u < PD; ++u) {
        dp_step_fwd(v, k, pf[u][0], pf[u][1], am, lane);
        if (u & 1) dp_rescale(v, k);
        int ri = min(t + u + PD, TT_ - 1);
        pf[u][0] = *(const f32x4*)(em + (size_t)ri * SPAD);
        pf[u][1] = *(const f32x4*)(em + (size_t)ri * SPAD + 4);
      }
    }
#pragma unroll
    for (int u = 0; u < PD; ++u) {
      if (t + u <= tm) {
        dp_step_fwd(v, k, pf[u][0], pf[u][1], am, lane);
        if (u & 1) dp_rescale(v, k);
      }
    }
  } else {
    // ---- backward ----
    float amB[4];
#pragma unroll
    for (int j = 0; j < 4; ++j) amB[j] = allow_f(tg, lane * 8 + 2 * j + 3);
    int s1 = 2 * Ll - 1, s2 = 2 * Ll;
#pragma unroll
    for (int r = 0; r < 8; ++r) {
      int s = lane * 8 + r;
      v[r] = (s == s1 || s == s2) ? 1.f : 0.f;
    }
#pragma unroll
    for (int j = 0; j < PD; ++j) {
      int ri = max(Tl - 1 - j, 0);
      pf[j][0] = *(const f32x4*)(em + (size_t)ri * SPAD);
      pf[j][1] = *(const f32x4*)(em + (size_t)ri * SPAD + 4);
    }
    int t = Tl - 1;
    for (; t - (PD - 1) > tm; t -= PD) {
#pragma unroll
      for (int u = 0; u < PD; ++u) {
        dp_step_bwd(v, k, pf[u][0], pf[u][1], amB, lane);
        if (u & 1) dp_rescale(v, k);
        int ri = max(t - u - PD, 0);
        pf[u][0] = *(const f32x4*)(em + (size_t)ri * SPAD);
        pf[u][1] = *(const f32x4*)(em + (size_t)ri * SPAD + 4);
      }
    }
#pragma unroll
    for (int u = 0; u < PD; ++u) {
      if (t - u > tm) {
        dp_step_bwd(v, k, pf[u][0], pf[u][1], amB, lane);
        if (u & 1) dp_rescale(v, k);
      }
    }
    // publish g_tm and its scale
#pragma unroll
    for (int r = 0; r < 8; ++r) sg[lane * 8 + r] = v[r];
    skg[lane] = k;
  }
  __syncthreads();
  if (wave == 0) {
    float p = 0.f;
#pragma unroll
    for (int r = 0; r < 8; ++r) p = fmaf(v[r], sg[lane * 8 + r], p);
    int kk = k + skg[lane];
    if (p == 0.f) kk = -(1 << 30);
#pragma unroll
    for (int d = 1; d < 64; d <<= 1) {
      float po = __shfl_xor(p, d);
      int ko = __shfl_xor(kk, d);
      int km = max(kk, ko);
      p = ldexpf(p, kk - km) + ldexpf(po, ko - km);
      kk = km;
    }
    if (lane == 0) {
      float nll = 0.f;
      if (p > 0.f) nll = -((log2f(p) + (float)kk) * 0.69314718055994531f);
      partial[b] = nll / (float)Tl;
    }
  }
}

__global__ void finalize_kernel(const float* __restrict__ partial,
                                float* __restrict__ out) {
  int l = threadIdx.x;
  float v = (l < BN_) ? partial[l] : 0.f;
#pragma unroll
  for (int d = 1; d < 64; d <<= 1) v += __shfl_xor(v, d);
  if (l == 0) out[0] = v * (1.f / BN_);
}

// ---------------------------------------------------------------------------
extern "C" void kernel_launch(void* const* d_in, const int* in_sizes, int n_in,
                              void* d_out, int out_size, void* d_ws, size_t ws_size,
                              hipStream_t stream) {
  const float* dec = (const float*)d_in[0];   // [B, D, T] f32
  const int* tgt   = (const int*)d_in[1];     // [B, LMAX]
  const int* dln   = (const int*)d_in[2];     // [B]
  const int* tln   = (const int*)d_in[3];     // [B]
  const float* W1  = (const float*)d_in[4];   // [D, D]
  const float* b1  = (const float*)d_in[5];   // [D]
  const float* W2  = (const float*)d_in[6];   // [D, V]
  const float* b2  = (const float*)d_in[7];   // [V]
  float* out = (float*)d_out;

  char* ws = (char*)d_ws;
  const size_t M = (size_t)BN_ * TT_;  // 32000
  _Float16* Af   = (_Float16*)(ws);                 // [M, D] f16
  float* EM      = (float*)(ws);                    // [B,T,SPAD] f32 (aliases Af)
  _Float16* Hf   = (_Float16*)(ws + 65536000);      // [M, D] f16
  _Float16* W1T  = (_Float16*)(ws + 131072000);     // [D, D] f16 (W1^T)
  _Float16* W2T  = (_Float16*)(ws + 133169152);     // [V, D] f16 (W2^T)
  float* LPp     = (float*)(ws + 133332992);        // [M, V] f32
  float* partial = (float*)(ws + 143572992);        // [B] f32

  dim3 tb(32, 8, 1);
  transpose_cast_kernel<<<dim3((TT_ + 31) / 32, DD_ / 32, BN_), tb, 0, stream>>>(dec, Af, DD_, TT_);
  transpose_cast_kernel<<<dim3(DD_ / 32, DD_ / 32, 1), tb, 0, stream>>>(W1, W1T, DD_, DD_);
  transpose_cast_kernel<<<dim3((VC_ + 31) / 32, DD_ / 32, 1), tb, 0, stream>>>(W2, W2T, DD_, VC_);

  gemm_relu_kernel<<<dim3(DD_ / 128, M / 128, 1), 256, 0, stream>>>(
      Af, W1T, b1, Hf, (int)M, DD_, DD_);
  gemm_lsm_kernel<<<dim3(M / 128, 1, 1), 256, 0, stream>>>(
      Hf, W2T, b2, LPp, (int)M, DD_);
  emit_kernel<<<dim3((BN_ * TT_ * SPAD) / 256, 1, 1), 256, 0, stream>>>(LPp, tgt, EM);
  ctc_dp_kernel<<<dim3(BN_, 1, 1), 128, 0, stream>>>(EM, tgt, dln, tln, partial);
  finalize_kernel<<<1, 64, 0, stream>>>(partial, out);
}

// Round 5
// 453.532 us; speedup vs baseline: 2.9077x; 1.0048x over previous
//
#include <hip/hip_runtime.h>
#include <cstdint>
#include <cstddef>

// Problem constants (fixed by the reference).
#define BN_ 32
#define DD_ 1024
#define TT_ 1000
#define LMAX_ 200
#define VC_ 80
#define BLANK_ 79
#define SS_ 401          // 2*LMAX+1
#define SPAD 512         // padded S: 64 lanes x 8 states
#define NEGV (-1e30f)

typedef _Float16 half8 __attribute__((ext_vector_type(8)));
typedef float f32x4 __attribute__((ext_vector_type(4)));

// Async global->LDS, 16B per lane. LDS dest is wave-uniform base + lane*16.
__device__ __forceinline__ void async16(const void* g, void* l) {
  __builtin_amdgcn_global_load_lds(
      (const __attribute__((address_space(1))) unsigned int*)g,
      (__attribute__((address_space(3))) unsigned int*)l, 16, 0, 0);
}

// ---------------------------------------------------------------------------
// Batched transpose + cast f32 -> f16: out[z][c][r] = (f16) in[z][r][c]
// ---------------------------------------------------------------------------
__global__ void transpose_cast_kernel(const float* __restrict__ in,
                                      _Float16* __restrict__ out,
                                      int R, int C) {
  __shared__ float tile[32][33];
  size_t bo = (size_t)blockIdx.z * R * C;
  int c0 = blockIdx.x * 32, r0 = blockIdx.y * 32;
  int tx = threadIdx.x, ty = threadIdx.y;
#pragma unroll
  for (int k = 0; k < 32; k += 8) {
    int r = r0 + ty + k, c = c0 + tx;
    if (r < R && c < C) tile[ty + k][tx] = in[bo + (size_t)r * C + c];
  }
  __syncthreads();
#pragma unroll
  for (int k = 0; k < 32; k += 8) {
    int c = c0 + ty + k, r = r0 + tx;
    if (c < C && r < R) out[bo + (size_t)c * R + r] = (_Float16)tile[tx][ty + k];
  }
}

// ---------------------------------------------------------------------------
// GEMM1: H = relu(A[M,K] @ W1[K,N] + b1). BK=64, XOR-swizzled LDS slots:
// global chunk cg (8 f16) of row stored at slot cg^(row&7). Fragment read
// hits slot (ku*4+quad)^(r16&7) -> bijective over the 8 bank-groups per
// 16-lane phase -> 2-way only (free, m136).
// ---------------------------------------------------------------------------
__global__ __launch_bounds__(256) void gemm_relu_kernel(
    const _Float16* __restrict__ A, const _Float16* __restrict__ Bt,
    const float* __restrict__ bias, _Float16* __restrict__ H,
    int M, int N, int K) {
  constexpr int BK = 64;
  __shared__ __align__(16) _Float16 sA[128 * BK];  // 16 KB
  __shared__ __align__(16) _Float16 sB[128 * BK];  // 16 KB
  int tid = threadIdx.x;
  int wave = tid >> 6, lane = tid & 63;
  int quad = lane >> 4, r16 = lane & 15;
  int m0 = blockIdx.y * 128, n0 = blockIdx.x * 128;
  int moff = (wave >> 1) * 64, noff = (wave & 1) * 64;

  f32x4 acc[4][4];
#pragma unroll
  for (int i = 0; i < 4; ++i)
#pragma unroll
    for (int j = 0; j < 4; ++j) acc[i][j] = {0.f, 0.f, 0.f, 0.f};

  for (int kt = 0; kt < K; kt += BK) {
#pragma unroll
    for (int jj = 0; jj < 4; ++jj) {
      int seg = tid + 256 * jj;          // 1024 16B segments per tile
      int row = seg >> 3, slot = seg & 7;
      int cg = slot ^ (row & 7);         // swizzled global chunk
      async16(A + (size_t)(m0 + row) * K + kt + cg * 8, &sA[seg * 8]);
      async16(Bt + (size_t)(n0 + row) * K + kt + cg * 8, &sB[seg * 8]);
    }
    __syncthreads();
#pragma unroll
    for (int ku = 0; ku < 2; ++ku) {
      int sw = ((ku * 4 + quad) ^ (r16 & 7)) * 8;
      half8 af[4], bfr[4];
#pragma unroll
      for (int i = 0; i < 4; ++i)
        af[i] = *(const half8*)&sA[(moff + i * 16 + r16) * BK + sw];
#pragma unroll
      for (int j = 0; j < 4; ++j)
        bfr[j] = *(const half8*)&sB[(noff + j * 16 + r16) * BK + sw];
#pragma unroll
      for (int i = 0; i < 4; ++i)
#pragma unroll
        for (int j = 0; j < 4; ++j)
          acc[i][j] = __builtin_amdgcn_mfma_f32_16x16x32_f16(af[i], bfr[j], acc[i][j], 0, 0, 0);
    }
    __syncthreads();
  }
#pragma unroll
  for (int j = 0; j < 4; ++j) {
    int n = n0 + noff + j * 16 + r16;
    float bv = bias[n];
#pragma unroll
    for (int i = 0; i < 4; ++i) {
#pragma unroll
      for (int r = 0; r < 4; ++r) {
        int m = m0 + moff + i * 16 + quad * 4 + r;
        float v = acc[i][j][r] + bv;
        v = fmaxf(v, 0.f);
        H[(size_t)m * N + n] = (_Float16)v;
      }
    }
  }
}

// ---------------------------------------------------------------------------
// GEMM2 + fused log_softmax. BK=64 + same swizzle. sB: 80 rows -> 640 segs
// (2 full jj iters + waves 0,1 of the third; whole-wave masking).
// ---------------------------------------------------------------------------
__global__ __launch_bounds__(256) void gemm_lsm_kernel(
    const _Float16* __restrict__ A, const _Float16* __restrict__ Bt,
    const float* __restrict__ bias, float* __restrict__ LP, int M, int K) {
  constexpr int BK = 64;
  __shared__ __align__(16) _Float16 sA[128 * BK];  // 16 KB
  __shared__ __align__(16) _Float16 sB[VC_ * BK];  // 10 KB
  int tid = threadIdx.x;
  int wave = tid >> 6, lane = tid & 63;
  int quad = lane >> 4, r16 = lane & 15;
  int m0 = blockIdx.x * 128;

  f32x4 acc[2][5];
#pragma unroll
  for (int i = 0; i < 2; ++i)
#pragma unroll
    for (int j = 0; j < 5; ++j) acc[i][j] = {0.f, 0.f, 0.f, 0.f};

  for (int kt = 0; kt < K; kt += BK) {
#pragma unroll
    for (int jj = 0; jj < 4; ++jj) {
      int seg = tid + 256 * jj;
      int row = seg >> 3, slot = seg & 7;
      int cg = slot ^ (row & 7);
      async16(A + (size_t)(m0 + row) * K + kt + cg * 8, &sA[seg * 8]);
    }
#pragma unroll
    for (int jj = 0; jj < 3; ++jj) {
      int seg = tid + 256 * jj;
      if (seg < VC_ * 8) {  // 640 segs; masks at whole-wave granularity
        int row = seg >> 3, slot = seg & 7;
        int cg = slot ^ (row & 7);
        async16(Bt + (size_t)row * K + kt + cg * 8, &sB[seg * 8]);
      }
    }
    __syncthreads();
#pragma unroll
    for (int ku = 0; ku < 2; ++ku) {
      int sw = ((ku * 4 + quad) ^ (r16 & 7)) * 8;
      half8 af[2], bfr[5];
#pragma unroll
      for (int i = 0; i < 2; ++i)
        af[i] = *(const half8*)&sA[(wave * 32 + i * 16 + r16) * BK + sw];
#pragma unroll
      for (int j = 0; j < 5; ++j)
        bfr[j] = *(const half8*)&sB[(j * 16 + r16) * BK + sw];
#pragma unroll
      for (int i = 0; i < 2; ++i)
#pragma unroll
        for (int j = 0; j < 5; ++j)
          acc[i][j] = __builtin_amdgcn_mfma_f32_16x16x32_f16(af[i], bfr[j], acc[i][j], 0, 0, 0);
    }
    __syncthreads();
  }
  float bv[5];
#pragma unroll
  for (int j = 0; j < 5; ++j) bv[j] = bias[j * 16 + r16];
#pragma unroll
  for (int i = 0; i < 2; ++i) {
#pragma unroll
    for (int rr = 0; rr < 4; ++rr) {
      float vals[5];
      float mx = -3.4e38f;
#pragma unroll
      for (int j = 0; j < 5; ++j) {
        vals[j] = acc[i][j][rr] + bv[j];
        mx = fmaxf(mx, vals[j]);
      }
#pragma unroll
      for (int d = 1; d < 16; d <<= 1) mx = fmaxf(mx, __shfl_xor(mx, d));
      float sm = 0.f;
#pragma unroll
      for (int j = 0; j < 5; ++j) sm += expf(vals[j] - mx);
#pragma unroll
      for (int d = 1; d < 16; d <<= 1) sm += __shfl_xor(sm, d);
      float lse = mx + logf(sm);
      int m = m0 + wave * 32 + i * 16 + quad * 4 + rr;
      float* o = LP + (size_t)m * VC_;
#pragma unroll
      for (int j = 0; j < 5; ++j) o[j * 16 + r16] = vals[j] - lse;
    }
  }
}

// ---------------------------------------------------------------------------
// Emit precompute: EM[b][t][s] = exp(LP[b][t][label(s)]) for s<SS_, else 0.
// ---------------------------------------------------------------------------
__global__ __launch_bounds__(256) void emit_kernel(
    const float* __restrict__ LP, const int* __restrict__ targets,
    float* __restrict__ EM) {
  int idx = blockIdx.x * 256 + threadIdx.x;
  int s = idx & (SPAD - 1);
  int bt = idx >> 9;
  float v = 0.f;
  if (s < SS_) {
    int lab = BLANK_;
    if (s & 1) {
      int b = bt / TT_;
      lab = targets[b * LMAX_ + (s >> 1)];
    }
    v = __expf(LP[(size_t)bt * VC_ + lab]);
  }
  EM[idx] = v;
}

// ---------------------------------------------------------------------------
// CTC DP, forward/backward split. Linear domain, PER-LANE block-float scale
// (R3-proven; wave-uniform scaling flushes the >87-nat inter-state spread).
// Block = 128 threads: wave 0 forward t=1..tm; wave 1 reverse t=Tl-1..tm+1.
// P = sum_s alpha_tm[s] * g_tm[s], scale-aware butterfly reduce.
// ---------------------------------------------------------------------------
__device__ __forceinline__ void dp_step_fwd(float (&bta)[8], int& k,
                                            const f32x4 e0, const f32x4 e1,
                                            const float (&am)[4], int lane) {
  float pm1 = __shfl_up(bta[7], 1);   // alpha[s0-1] (prev lane r=7)
  int pk = __shfl_up(k, 1);
  if (lane == 0) { pm1 = 0.f; pk = k; }
  int knew = max(k, pk);
  pm1 = ldexpf(pm1, pk - knew);
  int ds = k - knew;
#pragma unroll
  for (int r = 0; r < 8; ++r) bta[r] = ldexpf(bta[r], ds);
  k = knew;
  float nb[8];
  nb[0] = (bta[0] + pm1) * e0.x;
  nb[1] = fmaf(am[0], pm1, bta[1] + bta[0]) * e0.y;
  nb[2] = (bta[2] + bta[1]) * e0.z;
  nb[3] = fmaf(am[1], bta[1], bta[3] + bta[2]) * e0.w;
  nb[4] = (bta[4] + bta[3]) * e1.x;
  nb[5] = fmaf(am[2], bta[3], bta[5] + bta[4]) * e1.y;
  nb[6] = (bta[6] + bta[5]) * e1.z;
  nb[7] = fmaf(am[3], bta[5], bta[7] + bta[6]) * e1.w;
#pragma unroll
  for (int r = 0; r < 8; ++r) bta[r] = nb[r];
}

// reverse: g'[s] = gh[s] + gh[s+1] + allow(s+2)*gh[s+2],  gh = e . g
__device__ __forceinline__ void dp_step_bwd(float (&g)[8], int& k,
                                            const f32x4 e0, const f32x4 e1,
                                            const float (&amB)[4], int lane) {
  float gh[8];
  gh[0] = g[0] * e0.x; gh[1] = g[1] * e0.y;
  gh[2] = g[2] * e0.z; gh[3] = g[3] * e0.w;
  gh[4] = g[4] * e1.x; gh[5] = g[5] * e1.y;
  gh[6] = g[6] * e1.z; gh[7] = g[7] * e1.w;
  float qm1 = __shfl_down(gh[0], 1);  // next lane gh[0]
  float qm2 = __shfl_down(gh[1], 1);  // next lane gh[1]
  int nk = __shfl_down(k, 1);
  if (lane == 63) { qm1 = 0.f; qm2 = 0.f; nk = k; }
  int knew = max(k, nk);
  int dq = nk - knew;
  qm1 = ldexpf(qm1, dq);
  qm2 = ldexpf(qm2, dq);
  int ds = k - knew;
#pragma unroll
  for (int r = 0; r < 8; ++r) gh[r] = ldexpf(gh[r], ds);
  k = knew;
  g[0] = gh[0] + gh[1];
  g[1] = fmaf(amB[0], gh[3], gh[1] + gh[2]);
  g[2] = gh[2] + gh[3];
  g[3] = fmaf(amB[1], gh[5], gh[3] + gh[4]);
  g[4] = gh[4] + gh[5];
  g[5] = fmaf(amB[2], gh[7], gh[5] + gh[6]);
  g[6] = gh[6] + gh[7];
  g[7] = fmaf(amB[3], qm2, gh[7] + qm1);
}

__device__ __forceinline__ void dp_rescale(float (&v)[8], int& k) {
  float m = fmaxf(fmaxf(fmaxf(v[0], v[1]), fmaxf(v[2], v[3])),
                  fmaxf(fmaxf(v[4], v[5]), fmaxf(v[6], v[7])));
  int ex = (__float_as_int(m) >> 23) - 126;  // m>=0; m==0 -> harmless drift
  k += ex;
#pragma unroll
  for (int r = 0; r < 8; ++r) v[r] = ldexpf(v[r], -ex);
}

// allow(s) = s odd, s>=3, label(s)!=BLANK, label(s)!=label(s-2)
__device__ __forceinline__ float allow_f(const int* __restrict__ tg, int s) {
  if (!(s & 1) || s < 3) return 0.f;
  int li = s >> 1;
  if (li >= LMAX_) return 0.f;
  int lab = tg[li];
  return (lab != BLANK_ && lab != tg[li - 1]) ? 1.f : 0.f;
}

__global__ __launch_bounds__(128) void ctc_dp_kernel(
    const float* __restrict__ EM, const int* __restrict__ targets,
    const int* __restrict__ dlen, const int* __restrict__ tlen,
    float* __restrict__ partial) {
  __shared__ float sg[SPAD];
  __shared__ int skg[64];
  int b = blockIdx.x;
  int wave = threadIdx.x >> 6;
  int lane = threadIdx.x & 63;
  const float* em = EM + (size_t)b * TT_ * SPAD + lane * 8;
  const int* tg = targets + b * LMAX_;
  int Tl = dlen[b], Ll = tlen[b];
  int tm = Tl >> 1;  // forward owns e_0..e_tm, backward e_{tm+1}..e_{Tl-1}

  constexpr int PD = 8;
  f32x4 pf[PD][2];
  float v[8];
  int k = 0;

  if (wave == 0) {
    // ---- forward ----
    float am[4];
#pragma unroll
    for (int j = 0; j < 4; ++j) am[j] = allow_f(tg, lane * 8 + 2 * j + 1);
    f32x4 r0a = *(const f32x4*)(em);
#pragma unroll
    for (int r = 0; r < 8; ++r) v[r] = 0.f;
    if (lane == 0) { v[0] = r0a.x; v[1] = r0a.y; }
#pragma unroll
    for (int j = 0; j < PD; ++j) {
      int ri = min(1 + j, TT_ - 1);
      pf[j][0] = *(const f32x4*)(em + (size_t)ri * SPAD);
      pf[j][1] = *(const f32x4*)(em + (size_t)ri * SPAD + 4);
    }
    int t = 1;
    for (; t + (PD - 1) <= tm; t += PD) {
#pragma unroll
      for (int u = 0; u < PD; ++u) {
        dp_step_fwd(v, k, pf[u][0], pf[u][1], am, lane);
        if (u & 1) dp_rescale(v, k);
        int ri = min(t + u + PD, TT_ - 1);
        pf[u][0] = *(const f32x4*)(em + (size_t)ri * SPAD);
        pf[u][1] = *(const f32x4*)(em + (size_t)ri * SPAD + 4);
      }
    }
#pragma unroll
    for (int u = 0; u < PD; ++u) {
      if (t + u <= tm) {
        dp_step_fwd(v, k, pf[u][0], pf[u][1], am, lane);
        if (u & 1) dp_rescale(v, k);
      }
    }
  } else {
    // ---- backward ----
    float amB[4];
#pragma unroll
    for (int j = 0; j < 4; ++j) amB[j] = allow_f(tg, lane * 8 + 2 * j + 3);
    int s1 = 2 * Ll - 1, s2 = 2 * Ll;
#pragma unroll
    for (int r = 0; r < 8; ++r) {
      int s = lane * 8 + r;
      v[r] = (s == s1 || s == s2) ? 1.f : 0.f;
    }
#pragma unroll
    for (int j = 0; j < PD; ++j) {
      int ri = max(Tl - 1 - j, 0);
      pf[j][0] = *(const f32x4*)(em + (size_t)ri * SPAD);
      pf[j][1] = *(const f32x4*)(em + (size_t)ri * SPAD + 4);
    }
    int t = Tl - 1;
    for (; t - (PD - 1) > tm; t -= PD) {
#pragma unroll
      for (int u = 0; u < PD; ++u) {
        dp_step_bwd(v, k, pf[u][0], pf[u][1], amB, lane);
        if (u & 1) dp_rescale(v, k);
        int ri = max(t - u - PD, 0);
        pf[u][0] = *(const f32x4*)(em + (size_t)ri * SPAD);
        pf[u][1] = *(const f32x4*)(em + (size_t)ri * SPAD + 4);
      }
    }
#pragma unroll
    for (int u = 0; u < PD; ++u) {
      if (t - u > tm) {
        dp_step_bwd(v, k, pf[u][0], pf[u][1], amB, lane);
        if (u & 1) dp_rescale(v, k);
      }
    }
    // publish g_tm and its scale
#pragma unroll
    for (int r = 0; r < 8; ++r) sg[lane * 8 + r] = v[r];
    skg[lane] = k;
  }
  __syncthreads();
  if (wave == 0) {
    float p = 0.f;
#pragma unroll
    for (int r = 0; r < 8; ++r) p = fmaf(v[r], sg[lane * 8 + r], p);
    int kk = k + skg[lane];
    if (p == 0.f) kk = -(1 << 30);
#pragma unroll
    for (int d = 1; d < 64; d <<= 1) {
      float po = __shfl_xor(p, d);
      int ko = __shfl_xor(kk, d);
      int km = max(kk, ko);
      p = ldexpf(p, kk - km) + ldexpf(po, ko - km);
      kk = km;
    }
    if (lane == 0) {
      float nll = 0.f;
      if (p > 0.f) nll = -((log2f(p) + (float)kk) * 0.69314718055994531f);
      partial[b] = nll / (float)Tl;
    }
  }
}

__global__ void finalize_kernel(const float* __restrict__ partial,
                                float* __restrict__ out) {
  int l = threadIdx.x;
  float v = (l < BN_) ? partial[l] : 0.f;
#pragma unroll
  for (int d = 1; d < 64; d <<= 1) v += __shfl_xor(v, d);
  if (l == 0) out[0] = v * (1.f / BN_);
}

// ---------------------------------------------------------------------------
extern "C" void kernel_launch(void* const* d_in, const int* in_sizes, int n_in,
                              void* d_out, int out_size, void* d_ws, size_t ws_size,
                              hipStream_t stream) {
  const float* dec = (const float*)d_in[0];   // [B, D, T] f32
  const int* tgt   = (const int*)d_in[1];     // [B, LMAX]
  const int* dln   = (const int*)d_in[2];     // [B]
  const int* tln   = (const int*)d_in[3];     // [B]
  const float* W1  = (const float*)d_in[4];   // [D, D]
  const float* b1  = (const float*)d_in[5];   // [D]
  const float* W2  = (const float*)d_in[6];   // [D, V]
  const float* b2  = (const float*)d_in[7];   // [V]
  float* out = (float*)d_out;

  char* ws = (char*)d_ws;
  const size_t M = (size_t)BN_ * TT_;  // 32000
  _Float16* Af   = (_Float16*)(ws);                 // [M, D] f16
  float* EM      = (float*)(ws);                    // [B,T,SPAD] f32 (aliases Af)
  _Float16* Hf   = (_Float16*)(ws + 65536000);      // [M, D] f16
  _Float16* W1T  = (_Float16*)(ws + 131072000);     // [D, D] f16 (W1^T)
  _Float16* W2T  = (_Float16*)(ws + 133169152);     // [V, D] f16 (W2^T)
  float* LPp     = (float*)(ws + 133332992);        // [M, V] f32
  float* partial = (float*)(ws + 143572992);        // [B] f32

  dim3 tb(32, 8, 1);
  transpose_cast_kernel<<<dim3((TT_ + 31) / 32, DD_ / 32, BN_), tb, 0, stream>>>(dec, Af, DD_, TT_);
  transpose_cast_kernel<<<dim3(DD_ / 32, DD_ / 32, 1), tb, 0, stream>>>(W1, W1T, DD_, DD_);
  transpose_cast_kernel<<<dim3((VC_ + 31) / 32, DD_ / 32, 1), tb, 0, stream>>>(W2, W2T, DD_, VC_);

  gemm_relu_kernel<<<dim3(DD_ / 128, M / 128, 1), 256, 0, stream>>>(
      Af, W1T, b1, Hf, (int)M, DD_, DD_);
  gemm_lsm_kernel<<<dim3(M / 128, 1, 1), 256, 0, stream>>>(
      Hf, W2T, b2, LPp, (int)M, DD_);
  emit_kernel<<<dim3((BN_ * TT_ * SPAD) / 256, 1, 1), 256, 0, stream>>>(LPp, tgt, EM);
  ctc_dp_kernel<<<dim3(BN_, 1, 1), 128, 0, stream>>>(EM, tgt, dln, tln, partial);
  finalize_kernel<<<1, 64, 0, stream>>>(partial, out);
}

// Round 6
// 438.961 us; speedup vs baseline: 3.0042x; 1.0332x over previous
//
#include <hip/hip_runtime.h>
#include <cstdint>
#include <cstddef>

// Problem constants (fixed by the reference).
#define BN_ 32
#define DD_ 1024
#define TT_ 1000
#define LMAX_ 200
#define VC_ 80
#define BLANK_ 79
#define SS_ 401          // 2*LMAX+1
#define SPAD 512         // padded S: 64 lanes x 8 states
#define NEGV (-1e30f)

typedef _Float16 half8 __attribute__((ext_vector_type(8)));
typedef float f32x4 __attribute__((ext_vector_type(4)));

// Async global->LDS, 16B per lane. LDS dest is wave-uniform base + lane*16.
__device__ __forceinline__ void async16(const void* g, void* l) {
  __builtin_amdgcn_global_load_lds(
      (const __attribute__((address_space(1))) unsigned int*)g,
      (__attribute__((address_space(3))) unsigned int*)l, 16, 0, 0);
}

// ---------------------------------------------------------------------------
// Fused transpose+cast for all three inputs, one launch.
// z<32: dec slice z [1024,1000] -> Af[z] [1000,1024]
// z=32: W1 [1024,1024] -> W1T;  z=33: W2 [1024,80] -> W2T.  (R=1024 always)
// 64x64 tiles; loads 64-lane coalesced f32; stores 128B-contiguous f16 rows.
// ---------------------------------------------------------------------------
__global__ __launch_bounds__(256) void transpose_all_kernel(
    const float* __restrict__ dec, const float* __restrict__ W1,
    const float* __restrict__ W2, _Float16* __restrict__ Af,
    _Float16* __restrict__ W1T, _Float16* __restrict__ W2T) {
  __shared__ _Float16 T[64][72];  // [c][r], pad 72 keeps rows 16B-aligned
  int z = blockIdx.z;
  const float* in; _Float16* out; int C;
  const int R = 1024;
  if (z < 32) {
    in = dec + (size_t)z * R * TT_;
    out = Af + (size_t)z * TT_ * R;
    C = TT_;
  } else if (z == 32) {
    in = W1; out = W1T; C = 1024;
  } else {
    in = W2; out = W2T; C = VC_;
  }
  int c0 = blockIdx.x * 64, r0 = blockIdx.y * 64;
  if (c0 >= C) return;
  int tid = threadIdx.x;
  // Load: c = c0 + (tid&63); rows r0 + (tid>>6)*16 + i  (i=0..15)
  int cl = tid & 63, rg = tid >> 6;
  int c = c0 + cl;
  bool cv = (c < C);
  const float* ip = in + (size_t)(r0 + rg * 16) * C + c;
  _Float16 h[16];
#pragma unroll
  for (int i = 0; i < 16; ++i) h[i] = cv ? (_Float16)ip[(size_t)i * C] : (_Float16)0.f;
  *(half8*)&T[cl][rg * 16] = *(half8*)&h[0];
  *(half8*)&T[cl][rg * 16 + 8] = *(half8*)&h[8];
  __syncthreads();
  // Store: c_row = tid>>2, r-chunk = (tid&3)*16 -> 32B per thread, rows of
  // 128B formed by 4 consecutive threads.
  int cr = tid >> 2, rc = (tid & 3) * 16;
  if (c0 + cr < C) {
    half8 a = *(const half8*)&T[cr][rc];
    half8 b2 = *(const half8*)&T[cr][rc + 8];
    _Float16* op = out + (size_t)(c0 + cr) * R + r0 + rc;
    *(half8*)op = a;
    *(half8*)(op + 8) = b2;
  }
}

// ---------------------------------------------------------------------------
// GEMM1: H = relu(A[M,K] @ W1[K,N] + b1). BK=64, XOR-swizzled LDS (R5-proven).
// ---------------------------------------------------------------------------
__global__ __launch_bounds__(256) void gemm_relu_kernel(
    const _Float16* __restrict__ A, const _Float16* __restrict__ Bt,
    const float* __restrict__ bias, _Float16* __restrict__ H,
    int M, int N, int K) {
  constexpr int BK = 64;
  __shared__ __align__(16) _Float16 sA[128 * BK];  // 16 KB
  __shared__ __align__(16) _Float16 sB[128 * BK];  // 16 KB
  int tid = threadIdx.x;
  int wave = tid >> 6, lane = tid & 63;
  int quad = lane >> 4, r16 = lane & 15;
  int m0 = blockIdx.y * 128, n0 = blockIdx.x * 128;
  int moff = (wave >> 1) * 64, noff = (wave & 1) * 64;

  f32x4 acc[4][4];
#pragma unroll
  for (int i = 0; i < 4; ++i)
#pragma unroll
    for (int j = 0; j < 4; ++j) acc[i][j] = {0.f, 0.f, 0.f, 0.f};

  for (int kt = 0; kt < K; kt += BK) {
#pragma unroll
    for (int jj = 0; jj < 4; ++jj) {
      int seg = tid + 256 * jj;          // 1024 16B segments per tile
      int row = seg >> 3, slot = seg & 7;
      int cg = slot ^ (row & 7);         // swizzled global chunk
      async16(A + (size_t)(m0 + row) * K + kt + cg * 8, &sA[seg * 8]);
      async16(Bt + (size_t)(n0 + row) * K + kt + cg * 8, &sB[seg * 8]);
    }
    __syncthreads();
#pragma unroll
    for (int ku = 0; ku < 2; ++ku) {
      int sw = ((ku * 4 + quad) ^ (r16 & 7)) * 8;
      half8 af[4], bfr[4];
#pragma unroll
      for (int i = 0; i < 4; ++i)
        af[i] = *(const half8*)&sA[(moff + i * 16 + r16) * BK + sw];
#pragma unroll
      for (int j = 0; j < 4; ++j)
        bfr[j] = *(const half8*)&sB[(noff + j * 16 + r16) * BK + sw];
#pragma unroll
      for (int i = 0; i < 4; ++i)
#pragma unroll
        for (int j = 0; j < 4; ++j)
          acc[i][j] = __builtin_amdgcn_mfma_f32_16x16x32_f16(af[i], bfr[j], acc[i][j], 0, 0, 0);
    }
    __syncthreads();
  }
#pragma unroll
  for (int j = 0; j < 4; ++j) {
    int n = n0 + noff + j * 16 + r16;
    float bv = bias[n];
#pragma unroll
    for (int i = 0; i < 4; ++i) {
#pragma unroll
      for (int r = 0; r < 4; ++r) {
        int m = m0 + moff + i * 16 + quad * 4 + r;
        float v = acc[i][j][r] + bv;
        v = fmaxf(v, 0.f);
        H[(size_t)m * N + n] = (_Float16)v;
      }
    }
  }
}

// ---------------------------------------------------------------------------
// GEMM2 + fused SOFTMAX (writes probs, not log-probs). 64-row M-tiles
// (500 blocks = 2/CU) so staging chains overlap across blocks.
// ---------------------------------------------------------------------------
__global__ __launch_bounds__(256) void gemm_prob_kernel(
    const _Float16* __restrict__ A, const _Float16* __restrict__ Bt,
    const float* __restrict__ bias, float* __restrict__ P, int M, int K) {
  constexpr int BK = 64;
  __shared__ __align__(16) _Float16 sA[64 * BK];   // 8 KB
  __shared__ __align__(16) _Float16 sB[VC_ * BK];  // 10 KB
  int tid = threadIdx.x;
  int wave = tid >> 6, lane = tid & 63;
  int quad = lane >> 4, r16 = lane & 15;
  int m0 = blockIdx.x * 64;

  f32x4 acc[5];
#pragma unroll
  for (int j = 0; j < 5; ++j) acc[j] = {0.f, 0.f, 0.f, 0.f};

  for (int kt = 0; kt < K; kt += BK) {
#pragma unroll
    for (int jj = 0; jj < 2; ++jj) {
      int seg = tid + 256 * jj;  // 512 segs
      int row = seg >> 3, slot = seg & 7;
      int cg = slot ^ (row & 7);
      async16(A + (size_t)(m0 + row) * K + kt + cg * 8, &sA[seg * 8]);
    }
#pragma unroll
    for (int jj = 0; jj < 3; ++jj) {
      int seg = tid + 256 * jj;
      if (seg < VC_ * 8) {  // 640 segs; whole-wave masking
        int row = seg >> 3, slot = seg & 7;
        int cg = slot ^ (row & 7);
        async16(Bt + (size_t)row * K + kt + cg * 8, &sB[seg * 8]);
      }
    }
    __syncthreads();
#pragma unroll
    for (int ku = 0; ku < 2; ++ku) {
      int sw = ((ku * 4 + quad) ^ (r16 & 7)) * 8;
      half8 af = *(const half8*)&sA[(wave * 16 + r16) * BK + sw];
      half8 bfr[5];
#pragma unroll
      for (int j = 0; j < 5; ++j)
        bfr[j] = *(const half8*)&sB[(j * 16 + r16) * BK + sw];
#pragma unroll
      for (int j = 0; j < 5; ++j)
        acc[j] = __builtin_amdgcn_mfma_f32_16x16x32_f16(af, bfr[j], acc[j], 0, 0, 0);
    }
    __syncthreads();
  }
  float bv[5];
#pragma unroll
  for (int j = 0; j < 5; ++j) bv[j] = bias[j * 16 + r16];
#pragma unroll
  for (int rr = 0; rr < 4; ++rr) {
    float vals[5];
    float mx = -3.4e38f;
#pragma unroll
    for (int j = 0; j < 5; ++j) {
      vals[j] = acc[j][rr] + bv[j];
      mx = fmaxf(mx, vals[j]);
    }
#pragma unroll
    for (int d = 1; d < 16; d <<= 1) mx = fmaxf(mx, __shfl_xor(mx, d));
    float ex[5], sm = 0.f;
#pragma unroll
    for (int j = 0; j < 5; ++j) { ex[j] = __expf(vals[j] - mx); sm += ex[j]; }
#pragma unroll
    for (int d = 1; d < 16; d <<= 1) sm += __shfl_xor(sm, d);
    float rinv = 1.f / sm;
    int m = m0 + wave * 16 + quad * 4 + rr;
    float* o = P + (size_t)m * VC_;
#pragma unroll
    for (int j = 0; j < 5; ++j) o[j * 16 + r16] = ex[j] * rinv;
  }
}

// ---------------------------------------------------------------------------
// Emit gather (probs already exponentiated): EM[b][t][s] = P[b][t][label(s)].
// ---------------------------------------------------------------------------
__global__ __launch_bounds__(256) void emit_kernel(
    const float* __restrict__ P, const int* __restrict__ targets,
    float* __restrict__ EM) {
  int idx = blockIdx.x * 256 + threadIdx.x;
  int s = idx & (SPAD - 1);
  int bt = idx >> 9;
  float v = 0.f;
  if (s < SS_) {
    int lab = BLANK_;
    if (s & 1) {
      int b = bt / TT_;
      lab = targets[b * LMAX_ + (s >> 1)];
    }
    v = P[(size_t)bt * VC_ + lab];
  }
  EM[idx] = v;
}

// ---------------------------------------------------------------------------
// CTC DP, forward/backward split. Linear domain, PER-LANE block-float scale
// (R3/R5-proven). Epilogue: atomicAdd of nll/(Tl*B) into out[0] (pre-zeroed).
// ---------------------------------------------------------------------------
__device__ __forceinline__ void dp_step_fwd(float (&bta)[8], int& k,
                                            const f32x4 e0, const f32x4 e1,
                                            const float (&am)[4], int lane) {
  float pm1 = __shfl_up(bta[7], 1);   // alpha[s0-1] (prev lane r=7)
  int pk = __shfl_up(k, 1);
  if (lane == 0) { pm1 = 0.f; pk = k; }
  int knew = max(k, pk);
  pm1 = ldexpf(pm1, pk - knew);
  int ds = k - knew;
#pragma unroll
  for (int r = 0; r < 8; ++r) bta[r] = ldexpf(bta[r], ds);
  k = knew;
  float nb[8];
  nb[0] = (bta[0] + pm1) * e0.x;
  nb[1] = fmaf(am[0], pm1, bta[1] + bta[0]) * e0.y;
  nb[2] = (bta[2] + bta[1]) * e0.z;
  nb[3] = fmaf(am[1], bta[1], bta[3] + bta[2]) * e0.w;
  nb[4] = (bta[4] + bta[3]) * e1.x;
  nb[5] = fmaf(am[2], bta[3], bta[5] + bta[4]) * e1.y;
  nb[6] = (bta[6] + bta[5]) * e1.z;
  nb[7] = fmaf(am[3], bta[5], bta[7] + bta[6]) * e1.w;
#pragma unroll
  for (int r = 0; r < 8; ++r) bta[r] = nb[r];
}

__device__ __forceinline__ void dp_step_bwd(float (&g)[8], int& k,
                                            const f32x4 e0, const f32x4 e1,
                                            const float (&amB)[4], int lane) {
  float gh[8];
  gh[0] = g[0] * e0.x; gh[1] = g[1] * e0.y;
  gh[2] = g[2] * e0.z; gh[3] = g[3] * e0.w;
  gh[4] = g[4] * e1.x; gh[5] = g[5] * e1.y;
  gh[6] = g[6] * e1.z; gh[7] = g[7] * e1.w;
  float qm1 = __shfl_down(gh[0], 1);
  float qm2 = __shfl_down(gh[1], 1);
  int nk = __shfl_down(k, 1);
  if (lane == 63) { qm1 = 0.f; qm2 = 0.f; nk = k; }
  int knew = max(k, nk);
  int dq = nk - knew;
  qm1 = ldexpf(qm1, dq);
  qm2 = ldexpf(qm2, dq);
  int ds = k - knew;
#pragma unroll
  for (int r = 0; r < 8; ++r) gh[r] = ldexpf(gh[r], ds);
  k = knew;
  g[0] = gh[0] + gh[1];
  g[1] = fmaf(amB[0], gh[3], gh[1] + gh[2]);
  g[2] = gh[2] + gh[3];
  g[3] = fmaf(amB[1], gh[5], gh[3] + gh[4]);
  g[4] = gh[4] + gh[5];
  g[5] = fmaf(amB[2], gh[7], gh[5] + gh[6]);
  g[6] = gh[6] + gh[7];
  g[7] = fmaf(amB[3], qm2, gh[7] + qm1);
}

__device__ __forceinline__ void dp_rescale(float (&v)[8], int& k) {
  float m = fmaxf(fmaxf(fmaxf(v[0], v[1]), fmaxf(v[2], v[3])),
                  fmaxf(fmaxf(v[4], v[5]), fmaxf(v[6], v[7])));
  int ex = (__float_as_int(m) >> 23) - 126;  // m>=0; m==0 -> harmless drift
  k += ex;
#pragma unroll
  for (int r = 0; r < 8; ++r) v[r] = ldexpf(v[r], -ex);
}

__device__ __forceinline__ float allow_f(const int* __restrict__ tg, int s) {
  if (!(s & 1) || s < 3) return 0.f;
  int li = s >> 1;
  if (li >= LMAX_) return 0.f;
  int lab = tg[li];
  return (lab != BLANK_ && lab != tg[li - 1]) ? 1.f : 0.f;
}

__global__ __launch_bounds__(128) void ctc_dp_kernel(
    const float* __restrict__ EM, const int* __restrict__ targets,
    const int* __restrict__ dlen, const int* __restrict__ tlen,
    float* __restrict__ out) {
  __shared__ float sg[SPAD];
  __shared__ int skg[64];
  int b = blockIdx.x;
  int wave = threadIdx.x >> 6;
  int lane = threadIdx.x & 63;
  const float* em = EM + (size_t)b * TT_ * SPAD + lane * 8;
  const int* tg = targets + b * LMAX_;
  int Tl = dlen[b], Ll = tlen[b];
  int tm = Tl >> 1;

  constexpr int PD = 8;
  f32x4 pf[PD][2];
  float v[8];
  int k = 0;

  if (wave == 0) {
    float am[4];
#pragma unroll
    for (int j = 0; j < 4; ++j) am[j] = allow_f(tg, lane * 8 + 2 * j + 1);
    f32x4 r0a = *(const f32x4*)(em);
#pragma unroll
    for (int r = 0; r < 8; ++r) v[r] = 0.f;
    if (lane == 0) { v[0] = r0a.x; v[1] = r0a.y; }
#pragma unroll
    for (int j = 0; j < PD; ++j) {
      int ri = min(1 + j, TT_ - 1);
      pf[j][0] = *(const f32x4*)(em + (size_t)ri * SPAD);
      pf[j][1] = *(const f32x4*)(em + (size_t)ri * SPAD + 4);
    }
    int t = 1;
    for (; t + (PD - 1) <= tm; t += PD) {
#pragma unroll
      for (int u = 0; u < PD; ++u) {
        dp_step_fwd(v, k, pf[u][0], pf[u][1], am, lane);
        if (u & 1) dp_rescale(v, k);
        int ri = min(t + u + PD, TT_ - 1);
        pf[u][0] = *(const f32x4*)(em + (size_t)ri * SPAD);
        pf[u][1] = *(const f32x4*)(em + (size_t)ri * SPAD + 4);
      }
    }
#pragma unroll
    for (int u = 0; u < PD; ++u) {
      if (t + u <= tm) {
        dp_step_fwd(v, k, pf[u][0], pf[u][1], am, lane);
        if (u & 1) dp_rescale(v, k);
      }
    }
  } else {
    float amB[4];
#pragma unroll
    for (int j = 0; j < 4; ++j) amB[j] = allow_f(tg, lane * 8 + 2 * j + 3);
    int s1 = 2 * Ll - 1, s2 = 2 * Ll;
#pragma unroll
    for (int r = 0; r < 8; ++r) {
      int s = lane * 8 + r;
      v[r] = (s == s1 || s == s2) ? 1.f : 0.f;
    }
#pragma unroll
    for (int j = 0; j < PD; ++j) {
      int ri = max(Tl - 1 - j, 0);
      pf[j][0] = *(const f32x4*)(em + (size_t)ri * SPAD);
      pf[j][1] = *(const f32x4*)(em + (size_t)ri * SPAD + 4);
    }
    int t = Tl - 1;
    for (; t - (PD - 1) > tm; t -= PD) {
#pragma unroll
      for (int u = 0; u < PD; ++u) {
        dp_step_bwd(v, k, pf[u][0], pf[u][1], amB, lane);
        if (u & 1) dp_rescale(v, k);
        int ri = max(t - u - PD, 0);
        pf[u][0] = *(const f32x4*)(em + (size_t)ri * SPAD);
        pf[u][1] = *(const f32x4*)(em + (size_t)ri * SPAD + 4);
      }
    }
#pragma unroll
    for (int u = 0; u < PD; ++u) {
      if (t - u > tm) {
        dp_step_bwd(v, k, pf[u][0], pf[u][1], amB, lane);
        if (u & 1) dp_rescale(v, k);
      }
    }
#pragma unroll
    for (int r = 0; r < 8; ++r) sg[lane * 8 + r] = v[r];
    skg[lane] = k;
  }
  __syncthreads();
  if (wave == 0) {
    float p = 0.f;
#pragma unroll
    for (int r = 0; r < 8; ++r) p = fmaf(v[r], sg[lane * 8 + r], p);
    int kk = k + skg[lane];
    if (p == 0.f) kk = -(1 << 30);
#pragma unroll
    for (int d = 1; d < 64; d <<= 1) {
      float po = __shfl_xor(p, d);
      int ko = __shfl_xor(kk, d);
      int km = max(kk, ko);
      p = ldexpf(p, kk - km) + ldexpf(po, ko - km);
      kk = km;
    }
    if (lane == 0) {
      float nll = 0.f;
      if (p > 0.f) nll = -((log2f(p) + (float)kk) * 0.69314718055994531f);
      atomicAdd(out, nll / (float)Tl * (1.f / BN_));
    }
  }
}

// ---------------------------------------------------------------------------
extern "C" void kernel_launch(void* const* d_in, const int* in_sizes, int n_in,
                              void* d_out, int out_size, void* d_ws, size_t ws_size,
                              hipStream_t stream) {
  const float* dec = (const float*)d_in[0];   // [B, D, T] f32
  const int* tgt   = (const int*)d_in[1];     // [B, LMAX]
  const int* dln   = (const int*)d_in[2];     // [B]
  const int* tln   = (const int*)d_in[3];     // [B]
  const float* W1  = (const float*)d_in[4];   // [D, D]
  const float* b1  = (const float*)d_in[5];   // [D]
  const float* W2  = (const float*)d_in[6];   // [D, V]
  const float* b2  = (const float*)d_in[7];   // [V]
  float* out = (float*)d_out;

  char* ws = (char*)d_ws;
  const size_t M = (size_t)BN_ * TT_;  // 32000
  _Float16* Af   = (_Float16*)(ws);                 // [M, D] f16
  float* EM      = (float*)(ws);                    // [B,T,SPAD] f32 (aliases Af)
  _Float16* Hf   = (_Float16*)(ws + 65536000);      // [M, D] f16
  _Float16* W1T  = (_Float16*)(ws + 131072000);     // [D, D] f16 (W1^T)
  _Float16* W2T  = (_Float16*)(ws + 133169152);     // [V, D] f16 (W2^T)
  float* Pp      = (float*)(ws + 133332992);        // [M, V] f32 (probs)

  hipMemsetAsync(d_out, 0, sizeof(float), stream);

  transpose_all_kernel<<<dim3(16, 16, 34), 256, 0, stream>>>(
      dec, W1, W2, Af, W1T, W2T);
  gemm_relu_kernel<<<dim3(DD_ / 128, M / 128, 1), 256, 0, stream>>>(
      Af, W1T, b1, Hf, (int)M, DD_, DD_);
  gemm_prob_kernel<<<dim3(M / 64, 1, 1), 256, 0, stream>>>(
      Hf, W2T, b2, Pp, (int)M, DD_);
  emit_kernel<<<dim3((BN_ * TT_ * SPAD) / 256, 1, 1), 256, 0, stream>>>(Pp, tgt, EM);
  ctc_dp_kernel<<<dim3(BN_, 1, 1), 128, 0, stream>>>(EM, tgt, dln, tln, out);
}